// Round 5
// baseline (164.903 us; speedup 1.0000x reference)
//
#include <hip/hip_runtime.h>

#define IMG_H 512
#define IMG_W 512
#define IMGSZ (IMG_H * IMG_W)
#define NIMG 48                       // B*C
#define NB 16
#define NPOS 4096
#define DNPIX 12582912.0              // 48*512*512

#define RB 8                          // rows per band (one wave per band)
#define NBANDS (IMG_H / RB)           // 64
#define SSIM_BLOCKS (NIMG * NBANDS)   // 3072 (divisible by 8 -> XCD swizzle ok)
#define SAMP_BLOCKS (NPOS / 64)       // 64
#define TOTAL_BLOCKS (SSIM_BLOCKS + SAMP_BLOCKS)  // 3136

__device__ __forceinline__ float ssim_val(float Sx, float Sy, float Sxx,
                                          float Syy, float Sxy)
{
    const float inv121 = 1.0f / 121.0f;
    const float C1c = 1e-4f, C2c = 9e-4f;
    float mux = Sx * inv121, muy = Sy * inv121;
    float sgx = Sxx * inv121 - mux * mux;
    float sgy = Syy * inv121 - muy * muy;
    float sgxy = Sxy * inv121 - mux * muy;
    float num = (2.f * mux * muy + C1c) * (2.f * sgxy + C2c);
    float den = (mux * mux + muy * muy + C1c) * (sgx + sgy + C2c);
    return __fdividef(num, den);
}

__device__ __forceinline__ void load8(const float* __restrict__ base, float x[8])
{
    const float4* p = (const float4*)base;
    float4 a = p[0], b = p[1];
    x[0] = a.x; x[1] = a.y; x[2] = a.z; x[3] = a.w;
    x[4] = b.x; x[5] = b.y; x[6] = b.z; x[7] = b.w;
}

// Horizontal 11-tap window sums across lane-owned 8-col segments via shfl,
// then SSIM for the 8 output columns of this lane. No LDS.
__device__ __forceinline__ float horiz_ssim(const float V[5][8], int lane)
{
    float W[5][8];
#pragma unroll
    for (int q = 0; q < 5; ++q) {
        float A0 = V[q][0];
        float A1 = A0 + V[q][1];
        float A2 = A1 + V[q][2];
        float A3 = A2 + V[q][3];
        float A4 = A3 + V[q][4];
        float A5 = A4 + V[q][5];
        float A6 = A5 + V[q][6];
        float T  = A6 + V[q][7];
        float B1 = T - A0, B2 = T - A1, B3 = T - A2, B4 = T - A3;
        float B5 = T - A4, B6 = T - A5, B7 = T - A6;
        // left neighbor suffixes, right neighbor prefixes
        float LB3 = __shfl_up(B3, 1), LB4 = __shfl_up(B4, 1);
        float LB5 = __shfl_up(B5, 1), LB6 = __shfl_up(B6, 1);
        float LB7 = __shfl_up(B7, 1);
        float RA0 = __shfl_down(A0, 1), RA1 = __shfl_down(A1, 1);
        float RA2 = __shfl_down(A2, 1), RA3 = __shfl_down(A3, 1);
        float RA4 = __shfl_down(A4, 1);
        if (lane == 0)  { LB3 = LB4 = LB5 = LB6 = LB7 = 0.f; }  // cols <0 are 0
        if (lane == 63) { RA0 = RA1 = RA2 = RA3 = RA4 = 0.f; }  // cols >=512 are 0
        W[q][0] = LB3 + A5;
        W[q][1] = LB4 + A6;
        W[q][2] = LB5 + T;
        W[q][3] = LB6 + T + RA0;
        W[q][4] = LB7 + T + RA1;
        W[q][5] = T + RA2;
        W[q][6] = B1 + RA3;
        W[q][7] = B2 + RA4;
    }
    float s = 0.f;
#pragma unroll
    for (int j = 0; j < 8; ++j)
        s += ssim_val(W[0][j], W[1][j], W[2][j], W[3][j], W[4][j]);
    return s;
}

__global__ __launch_bounds__(64) void fused_kernel(
    const float* __restrict__ pred, const float* __restrict__ targ,
    const int* __restrict__ pos32, const float* __restrict__ imp,
    double* __restrict__ acc, unsigned int* __restrict__ cnt,
    float* __restrict__ out)
{
    const int lane = threadIdx.x;
    const int bid = blockIdx.x;
    float ssim_s = 0.f, perc = 0.f, samp = 0.f;

    if (bid >= SAMP_BLOCKS) {
        // ---------------- SSIM + perceptual ----------------
        int s_lin = bid - SAMP_BLOCKS;
        // bijective XCD swizzle: consecutive same-XCD blocks cover contiguous bands
        int s = (s_lin & 7) * (SSIM_BLOCKS / 8) + (s_lin >> 3);
        const int img = s >> 6;            // NBANDS == 64
        const int band = s & 63;
        const int rs = band * RB;
        const float* __restrict__ pimg = pred + (size_t)img * IMGSZ;
        const float* __restrict__ timg = targ + (size_t)img * IMGSZ;
        const int c0 = lane * 8;

        float V[5][8];
#pragma unroll
        for (int q = 0; q < 5; ++q)
#pragma unroll
            for (int k = 0; k < 8; ++k) V[q][k] = 0.f;

        // warm-up rows rs-5 .. rs+5 (zero outside image)
        for (int gr = rs - 5; gr <= rs + 5; ++gr) {
            if (gr < 0 || gr >= IMG_H) continue;
            float x[8], y[8];
            load8(pimg + (size_t)gr * IMG_W + c0, x);
            load8(timg + (size_t)gr * IMG_W + c0, y);
            bool pin = (gr >= rs);          // in-band rows counted once for perc
#pragma unroll
            for (int k = 0; k < 8; ++k) {
                V[0][k] += x[k];
                V[1][k] += y[k];
                V[2][k] = fmaf(x[k], x[k], V[2][k]);
                V[3][k] = fmaf(y[k], y[k], V[3][k]);
                V[4][k] = fmaf(x[k], y[k], V[4][k]);
                if (pin) perc += fabsf(x[k] - y[k]);
            }
        }
        ssim_s += horiz_ssim(V, lane);

        for (int r = 1; r < RB; ++r) {
            int ge = rs + r + 5;            // entering row
            int gl = rs + r - 6;            // leaving row
            float xe[8] = {0,0,0,0,0,0,0,0}, ye[8] = {0,0,0,0,0,0,0,0};
            float xl[8] = {0,0,0,0,0,0,0,0}, yl[8] = {0,0,0,0,0,0,0,0};
            if (ge < IMG_H) {
                load8(pimg + (size_t)ge * IMG_W + c0, xe);
                load8(timg + (size_t)ge * IMG_W + c0, ye);
            }
            if (gl >= 0) {
                load8(pimg + (size_t)gl * IMG_W + c0, xl);
                load8(timg + (size_t)gl * IMG_W + c0, yl);
            }
            bool pin = (ge < rs + RB);      // entering row inside this band
#pragma unroll
            for (int k = 0; k < 8; ++k) {
                V[0][k] += xe[k] - xl[k];
                V[1][k] += ye[k] - yl[k];
                V[2][k] += fmaf(xe[k], xe[k], -xl[k] * xl[k]);
                V[3][k] += fmaf(ye[k], ye[k], -yl[k] * yl[k]);
                V[4][k] += fmaf(xe[k], ye[k], -xl[k] * yl[k]);
                if (pin) perc += fabsf(xe[k] - ye[k]);
            }
            ssim_s += horiz_ssim(V, lane);
        }
    } else {
        // ---------------- sampled loss (64 blocks x 64 lanes = 4096) --------
        int n = bid * 64 + lane;
        // int64 vs int32 layout probe: odd words all-zero <=> int64
        unsigned long long ball = __ballot(pos32[2 * n + 1] != 0);
        int u, v;
        if (ball == 0ull) { u = pos32[4 * n]; v = pos32[4 * n + 2]; }
        else              { u = pos32[2 * n]; v = pos32[2 * n + 1]; }
        int off = u * IMG_W + v;
        float se = 0.f;
#pragma unroll 4
        for (int j = 0; j < NIMG; ++j) {
            float d = pred[(size_t)j * IMGSZ + off] - targ[(size_t)j * IMGSZ + off];
            se = fmaf(d, d, se);
        }
        float wsum = 0.f;
#pragma unroll 4
        for (int b = 0; b < NB; ++b)
            wsum += 1.0f / (imp[(size_t)b * IMGSZ + off] + 0.1f);
        samp = (wsum * (1.0f / 16.0f)) * (se * (1.0f / 48.0f));
    }

    // ---------------- wave reduction + atomics ----------------
#pragma unroll
    for (int o = 32; o > 0; o >>= 1) {
        ssim_s += __shfl_down(ssim_s, o);
        perc   += __shfl_down(perc, o);
        samp   += __shfl_down(samp, o);
    }
    if (lane == 0) {
        if (bid >= SAMP_BLOCKS) {
            atomicAdd(&acc[0], (double)ssim_s);
            atomicAdd(&acc[1], (double)perc);
        } else {
            atomicAdd(&acc[2], (double)samp);
        }
        __threadfence();
        unsigned int old = atomicAdd(cnt, 1u);
        if (old == TOTAL_BLOCKS - 1) {
            // last block: all atomics from all blocks are visible
            double s0 = atomicAdd(&acc[0], 0.0);
            double s1 = atomicAdd(&acc[1], 0.0);
            double s2 = atomicAdd(&acc[2], 0.0);
            double sampled = s2 / (double)NPOS;
            double perceptual = s1 / DNPIX;
            double structural = 1.0 - s0 / DNPIX;
            double total = 0.3 * sampled + 0.4 * perceptual + 0.2 * structural;
            out[0] = (float)total;
            out[1] = (float)sampled;
            out[2] = (float)perceptual;
            out[3] = (float)structural;
            out[4] = 0.0f;
        }
    }
}

extern "C" void kernel_launch(void* const* d_in, const int* in_sizes, int n_in,
                              void* d_out, int out_size, void* d_ws, size_t ws_size,
                              hipStream_t stream)
{
    const float* pred = (const float*)d_in[0];
    const float* targ = (const float*)d_in[1];
    const int* pos = (const int*)d_in[2];
    const float* imp = (const float*)d_in[3];
    float* out = (float*)d_out;
    double* acc = (double*)d_ws;                    // acc[0..2]
    unsigned int* cnt = (unsigned int*)(acc + 3);   // block counter

    hipMemsetAsync(d_ws, 0, 32, stream);
    hipLaunchKernelGGL(fused_kernel, dim3(TOTAL_BLOCKS), dim3(64), 0, stream,
                       pred, targ, pos, imp, acc, cnt, out);
}